// Round 10
// baseline (308.408 us; speedup 1.0000x reference)
//
#include <hip/hip_runtime.h>
#include <hip/hip_cooperative_groups.h>

namespace cg = cooperative_groups;

// Problem constants (fixed by the reference setup)
#define BB   2
#define DD   96
#define HH   96
#define WW   96
#define CINC 16
#define COUTC 32
#define KVOL 27
#define GRID_VOX (BB*DD*HH*WW)         // 1,769,472 voxels
#define NW (KVOL*CINC*COUTC)           // 13824 weights
#define VPT 8                          // voxels per thread in compact
#define CVB (256*VPT)                  // voxels per compact chunk = 2048
#define NCHUNK (GRID_VOX / CVB)        // 864 compact chunks
#define SWP 20                         // LDS B-row pitch in halfs (40 B)

typedef _Float16 half4 __attribute__((ext_vector_type(4)));
typedef _Float16 half8 __attribute__((ext_vector_type(8)));
typedef float    floatx16 __attribute__((ext_vector_type(16)));

// ---- shared conv tile body (inlined into both fused P3 and fallback conv) --
// Register budget (the R9 lesson): nid[27] + 2x3 half8 in flight (24) +
// dual acc (32, AGPR) + addressing ~= 103 unified <= 128 @ (256,4). No spills.
__device__ __forceinline__ void conv_tile(
        const _Float16* __restrict__ featH, const int* __restrict__ pc,
        const int* __restrict__ perm, const int* __restrict__ g,
        const _Float16* sW, float* __restrict__ out,
        int n, int tile, int m, int hf, float bval) {
    const int j = tile * 32 + m;          // j < n (n % 32 == 0)
    const int p = pc[j];
    const int x = p & 127, y = (p >> 7) & 127, z = (p >> 14) & 127, b = p >> 21;
    const int base = ((b * DD + z) * HH + y) * WW + x;
    const int pm = perm[j];
    const int hf8 = hf * 8;

    int nid[KVOL];                        // static reg array (fully unrolled)
#pragma unroll
    for (int kk = 0; kk < KVOL; ++kk) {
        const int dz = kk / 9 - 1, dy = (kk / 3) % 3 - 1, dx = kk % 3 - 1;
        int nz = z + dz, ny = y + dy, nx = x + dx;
        bool inb = ((unsigned)nz < DD) & ((unsigned)ny < HH) & ((unsigned)nx < WW);
        int addr = inb ? base + (dz * HH + dy) * WW + dx : 0;
        int v = g[addr];
        nid[kk] = inb ? v : n;            // empty/OOB -> zero row
    }

    floatx16 acc0, acc1;                  // dual acc halves the MFMA chain
#pragma unroll
    for (int i = 0; i < 16; ++i) { acc0[i] = bval; acc1[i] = 0.0f; }

    // Ping-pong A prefetch, groups of 3. Full unroll -> all indices constant.
    half8 av[2][3];
#pragma unroll
    for (int q = 0; q < 3; ++q)
        av[0][q] = *(const half8*)(featH + (size_t)nid[q] * CINC + hf8);
#pragma unroll
    for (int gq = 0; gq < 9; ++gq) {
        const int cur = gq & 1, nxt = cur ^ 1;
        if (gq < 8) {
#pragma unroll
            for (int q = 0; q < 3; ++q)
                av[nxt][q] = *(const half8*)(featH + (size_t)nid[(gq + 1) * 3 + q] * CINC + hf8);
        }
#pragma unroll
        for (int q = 0; q < 3; ++q) {
            const int kk = gq * 3 + q;
            const _Float16* bp = &sW[kk * 32 * SWP + m * SWP + hf8];
            half4 b0 = *(const half4*)bp;
            half4 b1 = *(const half4*)(bp + 4);
            half8 bf = {b0[0], b0[1], b0[2], b0[3], b1[0], b1[1], b1[2], b1[3]};
            if (kk & 1)
                acc1 = __builtin_amdgcn_mfma_f32_32x32x16_f16(av[cur][q], bf, acc1, 0, 0, 0);
            else
                acc0 = __builtin_amdgcn_mfma_f32_32x32x16_f16(av[cur][q], bf, acc0, 0, 0, 0);
        }
    }

    // Epilogue: reg i -> row r=(i&3)+8*(i>>2)+4*hf, col m; perm via shfl.
#pragma unroll
    for (int i = 0; i < 16; ++i) {
        int r = (i & 3) + 8 * (i >> 2) + 4 * hf;
        int row = __shfl(pm, r);          // lanes r and r+32 hold same pm
        out[(size_t)row * COUTC + m] = acc0[i] + acc1[i];
    }
}

// ===================== FUSED cooperative kernel (primary path) ===============
__global__ __launch_bounds__(256, 4) void fused_kernel(
        const float* __restrict__ feat, const int* __restrict__ idx,
        const float* __restrict__ w, const float* __restrict__ bias,
        int* __restrict__ g, _Float16* __restrict__ featH,
        int* __restrict__ pc, int* __restrict__ perm,
        int* __restrict__ counter, float* __restrict__ out, int n) {
    __shared__ _Float16 sW[KVOL * 32 * SWP];   // 34,560 B, lives across phases
    cg::grid_group grid = cg::this_grid();
    const int t = threadIdx.x;
    const int nblk = gridDim.x;

    // ---- P1a: stage weights into this block's LDS from fp32 w (L2-hot) ----
    for (int u = t; u < KVOL * 64; u += 256) {
        int kk = u >> 6, r = u & 63;
        int co = r >> 1, h = r & 1;
        half8 v;
#pragma unroll
        for (int q = 0; q < 8; ++q)
            v[q] = (_Float16)w[(co * CINC + h * 8 + q) * KVOL + kk];
        _Float16* dst = &sW[kk * 32 * SWP + co * SWP + h * 8];
        *(half4*)dst = half4{v[0], v[1], v[2], v[3]};
        *(half4*)(dst + 4) = half4{v[4], v[5], v[6], v[7]};
    }

    // ---- P1b: scatter point ids into grid (grid-stride over n) ----
    for (int i = blockIdx.x * 256 + t; i < n; i += nblk * 256) {
        int4 v = ((const int4*)idx)[i];   // (b, z, y, x)
        int lin = ((v.x * DD + v.y) * HH + v.z) * WW + v.w;
        g[lin] = i;
    }
    if (blockIdx.x == 0 && t == 0) {
        counter[0] = 0;
        half8 hz = {};
        half8* zr = (half8*)(featH + (size_t)n * CINC);
        zr[0] = hz; zr[1] = hz;           // zero row at featH[n]
    }
    grid.sync();

    // ---- P2: block-ordered compaction + in-place grid rewrite ----
    // Entry accepted only if pid<n AND idx[pid] round-trips to this voxel —
    // correct under arbitrary initial grid garbage (no pre-init needed).
    {
        __shared__ int s_wsum[4];
        __shared__ int s_wbase[4];
        __shared__ int s_base;
        const int lane = t & 63;
        const int wv = t >> 6;
        for (int chunk = blockIdx.x; chunk < NCHUNK; chunk += nblk) {
            const int base = chunk * CVB + t * VPT;

            int4 a0 = ((const int4*)(g + base))[0];
            int4 a1 = ((const int4*)(g + base))[1];
            int vals[VPT] = {a0.x, a0.y, a0.z, a0.w, a1.x, a1.y, a1.z, a1.w};
            int pid[VPT], pck[VPT];
            int cnt = 0;
#pragma unroll
            for (int q = 0; q < VPT; ++q) {   // static indices only
                int p = vals[q];
                bool ok = ((unsigned)p < (unsigned)n);
                int pk = 0;
                if (ok) {
                    int4 c = ((const int4*)idx)[p];
                    int lin = ((c.x * DD + c.y) * HH + c.z) * WW + c.w;
                    ok = (lin == base + q);
                    pk = (c.x << 21) | (c.y << 14) | (c.z << 7) | c.w;
                }
                pid[q] = ok ? p : -1;
                pck[q] = pk;
                cnt += ok ? 1 : 0;
            }

            int incl = cnt;                   // wave shfl-scan
#pragma unroll
            for (int d = 1; d < 64; d <<= 1) {
                int v = __shfl_up(incl, d);
                if (lane >= d) incl += v;
            }
            if (lane == 63) s_wsum[wv] = incl;
            __syncthreads();
            if (t == 0) {
                int t0 = s_wsum[0], t1 = s_wsum[1], t2 = s_wsum[2], t3 = s_wsum[3];
                s_wbase[0] = 0; s_wbase[1] = t0; s_wbase[2] = t0 + t1;
                s_wbase[3] = t0 + t1 + t2;
                s_base = atomicAdd(counter, t0 + t1 + t2 + t3);
            }
            __syncthreads();
            int o = s_base + s_wbase[wv] + incl - cnt;

#pragma unroll
            for (int q = 0; q < VPT; ++q) {
                int tag = n;                  // empty marker -> zero row
                int p = pid[q];
                if (p >= 0) {
                    pc[o] = pck[q];
                    perm[o] = p;
                    const float4* src = (const float4*)(feat + (size_t)p * CINC);
                    float4 f0 = src[0], f1 = src[1], f2 = src[2], f3 = src[3];
                    half8 h0, h1;
                    h0[0]=(_Float16)f0.x; h0[1]=(_Float16)f0.y; h0[2]=(_Float16)f0.z; h0[3]=(_Float16)f0.w;
                    h0[4]=(_Float16)f1.x; h0[5]=(_Float16)f1.y; h0[6]=(_Float16)f1.z; h0[7]=(_Float16)f1.w;
                    h1[0]=(_Float16)f2.x; h1[1]=(_Float16)f2.y; h1[2]=(_Float16)f2.z; h1[3]=(_Float16)f2.w;
                    h1[4]=(_Float16)f3.x; h1[5]=(_Float16)f3.y; h1[6]=(_Float16)f3.z; h1[7]=(_Float16)f3.w;
                    half8* dst = (half8*)(featH + (size_t)o * CINC);
                    dst[0] = h0; dst[1] = h1;
                    tag = o;
                    ++o;
                }
                g[base + q] = tag;
            }
        }
    }
    grid.sync();

    // ---- P3: implicit-GEMM conv. wave = 32 points x 32 couts, grid-stride --
    const int lane = t & 63;
    const int wave = t >> 6;
    const int m    = lane & 31;
    const int hf   = lane >> 5;
    const float bval = bias[m];
    const int ntile = n >> 5;             // n % 32 == 0 (200000)

#pragma unroll 1
    for (int tile = blockIdx.x * 4 + wave; tile < ntile; tile += nblk * 4)
        conv_tile(featH, pc, perm, g, sW, out, n, tile, m, hf, bval);
}

// ===================== Fallback path (3-dispatch, launch-failure only) =======
__global__ __launch_bounds__(256) void setup_kernel(
        const int* __restrict__ idx, int* __restrict__ g,
        const float* __restrict__ w, _Float16* __restrict__ wH,
        int* __restrict__ counter, int n, int scatter_blocks) {
    if ((int)blockIdx.x < scatter_blocks) {
        int i = blockIdx.x * 256 + threadIdx.x;
        if (i >= n) return;
        int4 v = ((const int4*)idx)[i];
        int lin = ((v.x * DD + v.y) * HH + v.z) * WW + v.w;
        g[lin] = i;
    } else {
        int t = ((int)blockIdx.x - scatter_blocks) * 256 + threadIdx.x;
        if (t == 0) counter[0] = 0;
        if (t >= NW) return;              // t = kk*512 + co*16 + ci
        int ci = t & (CINC - 1);
        int co = (t >> 4) & (COUTC - 1);
        int kk = t >> 9;
        wH[t] = (_Float16)w[(co * CINC + ci) * KVOL + kk];
    }
}

__global__ __launch_bounds__(256) void compact_kernel(
        const int* __restrict__ idx, const float* __restrict__ feat,
        int* __restrict__ g, _Float16* __restrict__ featH,
        int* __restrict__ pc, int* __restrict__ perm,
        int* __restrict__ counter, int n) {
    __shared__ int s_wsum[4];
    __shared__ int s_wbase[4];
    __shared__ int s_base;
    const int t = threadIdx.x;
    const int lane = t & 63;
    const int wv = t >> 6;
    const int base = blockIdx.x * CVB + t * VPT;

    int4 a0 = ((const int4*)(g + base))[0];
    int4 a1 = ((const int4*)(g + base))[1];
    int vals[VPT] = {a0.x, a0.y, a0.z, a0.w, a1.x, a1.y, a1.z, a1.w};
    int pid[VPT], pck[VPT];
    int cnt = 0;
#pragma unroll
    for (int q = 0; q < VPT; ++q) {
        int p = vals[q];
        bool ok = ((unsigned)p < (unsigned)n);
        int pk = 0;
        if (ok) {
            int4 c = ((const int4*)idx)[p];
            int lin = ((c.x * DD + c.y) * HH + c.z) * WW + c.w;
            ok = (lin == base + q);
            pk = (c.x << 21) | (c.y << 14) | (c.z << 7) | c.w;
        }
        pid[q] = ok ? p : -1;
        pck[q] = pk;
        cnt += ok ? 1 : 0;
    }
    int incl = cnt;
#pragma unroll
    for (int d = 1; d < 64; d <<= 1) {
        int v = __shfl_up(incl, d);
        if (lane >= d) incl += v;
    }
    if (lane == 63) s_wsum[wv] = incl;
    __syncthreads();
    if (t == 0) {
        int t0 = s_wsum[0], t1 = s_wsum[1], t2 = s_wsum[2], t3 = s_wsum[3];
        s_wbase[0] = 0; s_wbase[1] = t0; s_wbase[2] = t0 + t1;
        s_wbase[3] = t0 + t1 + t2;
        s_base = atomicAdd(counter, t0 + t1 + t2 + t3);
    }
    __syncthreads();
    int o = s_base + s_wbase[wv] + incl - cnt;
#pragma unroll
    for (int q = 0; q < VPT; ++q) {
        int tag = n;
        int p = pid[q];
        if (p >= 0) {
            pc[o] = pck[q];
            perm[o] = p;
            const float4* src = (const float4*)(feat + (size_t)p * CINC);
            float4 f0 = src[0], f1 = src[1], f2 = src[2], f3 = src[3];
            half8 h0, h1;
            h0[0]=(_Float16)f0.x; h0[1]=(_Float16)f0.y; h0[2]=(_Float16)f0.z; h0[3]=(_Float16)f0.w;
            h0[4]=(_Float16)f1.x; h0[5]=(_Float16)f1.y; h0[6]=(_Float16)f1.z; h0[7]=(_Float16)f1.w;
            h1[0]=(_Float16)f2.x; h1[1]=(_Float16)f2.y; h1[2]=(_Float16)f2.z; h1[3]=(_Float16)f2.w;
            h1[4]=(_Float16)f3.x; h1[5]=(_Float16)f3.y; h1[6]=(_Float16)f3.z; h1[7]=(_Float16)f3.w;
            half8* dst = (half8*)(featH + (size_t)o * CINC);
            dst[0] = h0; dst[1] = h1;
            tag = o;
            ++o;
        }
        g[base + q] = tag;
    }
    if (blockIdx.x == 0 && t == 0) {
        half8* zr = (half8*)(featH + (size_t)n * CINC);
        half8 hz = {};
        zr[0] = hz; zr[1] = hz;
    }
}

__global__ __launch_bounds__(256, 4) void conv_mfma_kernel(
        const _Float16* __restrict__ featH, const int* __restrict__ pc,
        const int* __restrict__ perm, const _Float16* __restrict__ wH,
        const float* __restrict__ bias, const int* __restrict__ g,
        float* __restrict__ out, int n) {
    __shared__ _Float16 sW[KVOL * 32 * SWP];
    for (int u = threadIdx.x; u < KVOL * 64; u += 256) {
        int kk = u >> 6, r = u & 63;
        int co = r >> 1, h = r & 1;
        const half4* src = (const half4*)(wH + kk * (COUTC * CINC) + co * CINC + h * 8);
        half4 v0 = src[0], v1 = src[1];
        _Float16* dst = &sW[kk * 32 * SWP + co * SWP + h * 8];
        *(half4*)dst = v0;
        *(half4*)(dst + 4) = v1;
    }
    __syncthreads();

    const int lane = threadIdx.x & 63;
    const int wave = threadIdx.x >> 6;
    const int m    = lane & 31;
    const int hf   = lane >> 5;
    const int tile = blockIdx.x * 4 + wave;
    if (tile * 32 >= n) return;
    conv_tile(featH, pc, perm, g, sW, out, n, tile, m, hf, bias[m]);
}

extern "C" void kernel_launch(void* const* d_in, const int* in_sizes, int n_in,
                              void* d_out, int out_size, void* d_ws, size_t ws_size,
                              hipStream_t stream) {
    const float* feat  = (const float*)d_in[0];   // [N,16] fp32
    const int*   idx   = (const int*)d_in[1];     // [N,4]  int32
    const float* convw = (const float*)d_in[2];   // [32,16,3,3,3] fp32
    const float* convb = (const float*)d_in[3];   // [32] fp32
    float* out = (float*)d_out;

    int n = in_sizes[1] / 4;                      // 200000

    // workspace layout (all 16B-aligned)
    char* ws = (char*)d_ws;
    int*      g       = (int*)ws;                               // 7,077,888 B
    int*      counter = (int*)(ws + GRID_VOX * 4);              //       256 B pad
    int*      pc      = (int*)(ws + GRID_VOX * 4 + 256);        //   n*4 B
    int*      perm    = pc + n;                                 //   n*4 B
    _Float16* featH   = (_Float16*)(perm + n);                  // (n+1)*32 B
    _Float16* wH      = featH + (size_t)(n + 1) * CINC;         //  NW*2 B (fallback)

    // Size the cooperative grid from the runtime's own occupancy math
    // (host-side queries only — capture-safe).
    int dev = 0, ncu = 0, maxb = 0;
    hipGetDevice(&dev);
    hipDeviceGetAttribute(&ncu, hipDeviceAttributeMultiprocessorCount, dev);
    hipError_t oe = hipOccupancyMaxActiveBlocksPerMultiprocessor(
        &maxb, fused_kernel, 256, 0);

    hipError_t le = hipErrorUnknown;
    if (oe == hipSuccess && maxb > 0 && ncu > 0) {
        int nblk = maxb * ncu;
        if (nblk > 2048) nblk = 2048;
        void* args[] = { (void*)&feat, (void*)&idx, (void*)&convw, (void*)&convb,
                         (void*)&g, (void*)&featH, (void*)&pc, (void*)&perm,
                         (void*)&counter, (void*)&out, (void*)&n };
        le = hipLaunchCooperativeKernel((void*)fused_kernel,
                                        dim3(nblk), dim3(256), args, 0, stream);
    }

    if (le != hipSuccess) {
        // 3-dispatch fallback.
        const int sb = (n + 255) / 256;
        const int rb = (NW + 255) / 256;
        setup_kernel<<<sb + rb, 256, 0, stream>>>(idx, g, convw, wH, counter, n, sb);
        compact_kernel<<<GRID_VOX / CVB, 256, 0, stream>>>(
            idx, feat, g, featH, pc, perm, counter, n);
        const int waves = (n + 31) / 32;
        conv_mfma_kernel<<<(waves + 3) / 4, 256, 0, stream>>>(
            featH, pc, perm, wH, convb, g, out, n);
    }
}

// Round 11
// 253.861 us; speedup vs baseline: 1.2149x; 1.2149x over previous
//
#include <hip/hip_runtime.h>
#include <hip/hip_cooperative_groups.h>

namespace cg = cooperative_groups;

// Problem constants (fixed by the reference setup)
#define BB   2
#define DD   96
#define HH   96
#define WW   96
#define CINC 16
#define COUTC 32
#define KVOL 27
#define GRID_VOX (BB*DD*HH*WW)         // 1,769,472 voxels
#define NW (KVOL*CINC*COUTC)           // 13824 weights
#define VPT 8                          // voxels per thread in compact
#define CVB (256*VPT)                  // voxels per compact chunk = 2048
#define NCHUNK (GRID_VOX / CVB)        // 864 compact chunks
#define SWP 20                         // LDS B-row pitch in halfs (40 B)

typedef _Float16 half4 __attribute__((ext_vector_type(4)));
typedef _Float16 half8 __attribute__((ext_vector_type(8)));
typedef float    floatx16 __attribute__((ext_vector_type(16)));

// ---- shared conv tile body (inlined into both fused P3 and fallback conv) --
// R10 lesson: at (256,4) the 128-unified budget splits 64 arch / 64 acc and
// the ~110 arch-live set spills (~220MB scratch traffic, 650 GB/s, VALU 2%).
// (256,3) -> ~170 unified -> fits with slack.
__device__ __forceinline__ void conv_tile(
        const _Float16* __restrict__ featH, const int* __restrict__ pc,
        const int* __restrict__ perm, const int* __restrict__ g,
        const _Float16* sW, float* __restrict__ out,
        int n, int tile, int m, int hf, float bval) {
    const int j = tile * 32 + m;          // j < n (n % 32 == 0)
    const int p = pc[j];
    const int x = p & 127, y = (p >> 7) & 127, z = (p >> 14) & 127, b = p >> 21;
    const int base = ((b * DD + z) * HH + y) * WW + x;
    const int pm = perm[j];
    const int hf8 = hf * 8;

    int nid[KVOL];                        // static reg array (fully unrolled)
#pragma unroll
    for (int kk = 0; kk < KVOL; ++kk) {
        const int dz = kk / 9 - 1, dy = (kk / 3) % 3 - 1, dx = kk % 3 - 1;
        int nz = z + dz, ny = y + dy, nx = x + dx;
        bool inb = ((unsigned)nz < DD) & ((unsigned)ny < HH) & ((unsigned)nx < WW);
        int addr = inb ? base + (dz * HH + dy) * WW + dx : 0;
        int v = g[addr];
        nid[kk] = inb ? v : n;            // empty/OOB -> zero row
    }

    floatx16 acc0, acc1;                  // dual acc halves the MFMA chain
#pragma unroll
    for (int i = 0; i < 16; ++i) { acc0[i] = bval; acc1[i] = 0.0f; }

    // Ping-pong A prefetch, groups of 3. Full unroll -> all indices constant.
    half8 av[2][3];
#pragma unroll
    for (int q = 0; q < 3; ++q)
        av[0][q] = *(const half8*)(featH + (size_t)nid[q] * CINC + hf8);
#pragma unroll
    for (int gq = 0; gq < 9; ++gq) {
        const int cur = gq & 1, nxt = cur ^ 1;
        if (gq < 8) {
#pragma unroll
            for (int q = 0; q < 3; ++q)
                av[nxt][q] = *(const half8*)(featH + (size_t)nid[(gq + 1) * 3 + q] * CINC + hf8);
        }
#pragma unroll
        for (int q = 0; q < 3; ++q) {
            const int kk = gq * 3 + q;
            const _Float16* bp = &sW[kk * 32 * SWP + m * SWP + hf8];
            half4 b0 = *(const half4*)bp;
            half4 b1 = *(const half4*)(bp + 4);
            half8 bf = {b0[0], b0[1], b0[2], b0[3], b1[0], b1[1], b1[2], b1[3]};
            if (kk & 1)
                acc1 = __builtin_amdgcn_mfma_f32_32x32x16_f16(av[cur][q], bf, acc1, 0, 0, 0);
            else
                acc0 = __builtin_amdgcn_mfma_f32_32x32x16_f16(av[cur][q], bf, acc0, 0, 0, 0);
        }
    }

    // Epilogue: reg i -> row r=(i&3)+8*(i>>2)+4*hf, col m; perm via shfl.
#pragma unroll
    for (int i = 0; i < 16; ++i) {
        int r = (i & 3) + 8 * (i >> 2) + 4 * hf;
        int row = __shfl(pm, r);          // lanes r and r+32 hold same pm
        out[(size_t)row * COUTC + m] = acc0[i] + acc1[i];
    }
}

// ===================== FUSED cooperative kernel (primary path) ===============
__global__ __launch_bounds__(256, 3) void fused_kernel(
        const float* __restrict__ feat, const int* __restrict__ idx,
        const float* __restrict__ w, const float* __restrict__ bias,
        int* __restrict__ g, _Float16* __restrict__ featH,
        int* __restrict__ pc, int* __restrict__ perm,
        int* __restrict__ counter, float* __restrict__ out, int n) {
    __shared__ _Float16 sW[KVOL * 32 * SWP];   // 34,560 B, lives across phases
    cg::grid_group grid = cg::this_grid();
    const int t = threadIdx.x;
    const int nblk = gridDim.x;

    // ---- P1a: stage weights into this block's LDS from fp32 w (L2-hot) ----
    for (int u = t; u < KVOL * 64; u += 256) {
        int kk = u >> 6, r = u & 63;
        int co = r >> 1, h = r & 1;
        half8 v;
#pragma unroll
        for (int q = 0; q < 8; ++q)
            v[q] = (_Float16)w[(co * CINC + h * 8 + q) * KVOL + kk];
        _Float16* dst = &sW[kk * 32 * SWP + co * SWP + h * 8];
        *(half4*)dst = half4{v[0], v[1], v[2], v[3]};
        *(half4*)(dst + 4) = half4{v[4], v[5], v[6], v[7]};
    }

    // ---- P1b: scatter point ids into grid (grid-stride over n) ----
    for (int i = blockIdx.x * 256 + t; i < n; i += nblk * 256) {
        int4 v = ((const int4*)idx)[i];   // (b, z, y, x)
        int lin = ((v.x * DD + v.y) * HH + v.z) * WW + v.w;
        g[lin] = i;
    }
    if (blockIdx.x == 0 && t == 0) {
        counter[0] = 0;
        half8 hz = {};
        half8* zr = (half8*)(featH + (size_t)n * CINC);
        zr[0] = hz; zr[1] = hz;           // zero row at featH[n]
    }
    grid.sync();

    // ---- P2: block-ordered compaction + in-place grid rewrite ----
    // Entry accepted only if pid<n AND idx[pid] round-trips to this voxel —
    // correct under arbitrary initial grid garbage (no pre-init needed).
    {
        __shared__ int s_wsum[4];
        __shared__ int s_wbase[4];
        __shared__ int s_base;
        const int lane = t & 63;
        const int wv = t >> 6;
        for (int chunk = blockIdx.x; chunk < NCHUNK; chunk += nblk) {
            const int base = chunk * CVB + t * VPT;

            int4 a0 = ((const int4*)(g + base))[0];
            int4 a1 = ((const int4*)(g + base))[1];
            int vals[VPT] = {a0.x, a0.y, a0.z, a0.w, a1.x, a1.y, a1.z, a1.w};
            int pid[VPT], pck[VPT];
            int cnt = 0;
#pragma unroll
            for (int q = 0; q < VPT; ++q) {   // static indices only
                int p = vals[q];
                bool ok = ((unsigned)p < (unsigned)n);
                int pk = 0;
                if (ok) {
                    int4 c = ((const int4*)idx)[p];
                    int lin = ((c.x * DD + c.y) * HH + c.z) * WW + c.w;
                    ok = (lin == base + q);
                    pk = (c.x << 21) | (c.y << 14) | (c.z << 7) | c.w;
                }
                pid[q] = ok ? p : -1;
                pck[q] = pk;
                cnt += ok ? 1 : 0;
            }

            int incl = cnt;                   // wave shfl-scan
#pragma unroll
            for (int d = 1; d < 64; d <<= 1) {
                int v = __shfl_up(incl, d);
                if (lane >= d) incl += v;
            }
            if (lane == 63) s_wsum[wv] = incl;
            __syncthreads();
            if (t == 0) {
                int t0 = s_wsum[0], t1 = s_wsum[1], t2 = s_wsum[2], t3 = s_wsum[3];
                s_wbase[0] = 0; s_wbase[1] = t0; s_wbase[2] = t0 + t1;
                s_wbase[3] = t0 + t1 + t2;
                s_base = atomicAdd(counter, t0 + t1 + t2 + t3);
            }
            __syncthreads();
            int o = s_base + s_wbase[wv] + incl - cnt;

#pragma unroll
            for (int q = 0; q < VPT; ++q) {
                int tag = n;                  // empty marker -> zero row
                int p = pid[q];
                if (p >= 0) {
                    pc[o] = pck[q];
                    perm[o] = p;
                    const float4* src = (const float4*)(feat + (size_t)p * CINC);
                    float4 f0 = src[0], f1 = src[1], f2 = src[2], f3 = src[3];
                    half8 h0, h1;
                    h0[0]=(_Float16)f0.x; h0[1]=(_Float16)f0.y; h0[2]=(_Float16)f0.z; h0[3]=(_Float16)f0.w;
                    h0[4]=(_Float16)f1.x; h0[5]=(_Float16)f1.y; h0[6]=(_Float16)f1.z; h0[7]=(_Float16)f1.w;
                    h1[0]=(_Float16)f2.x; h1[1]=(_Float16)f2.y; h1[2]=(_Float16)f2.z; h1[3]=(_Float16)f2.w;
                    h1[4]=(_Float16)f3.x; h1[5]=(_Float16)f3.y; h1[6]=(_Float16)f3.z; h1[7]=(_Float16)f3.w;
                    half8* dst = (half8*)(featH + (size_t)o * CINC);
                    dst[0] = h0; dst[1] = h1;
                    tag = o;
                    ++o;
                }
                g[base + q] = tag;
            }
        }
    }
    grid.sync();

    // ---- P3: implicit-GEMM conv. wave = 32 points x 32 couts, grid-stride --
    const int lane = t & 63;
    const int wave = t >> 6;
    const int m    = lane & 31;
    const int hf   = lane >> 5;
    const float bval = bias[m];
    const int ntile = n >> 5;             // n % 32 == 0 (200000)

#pragma unroll 1
    for (int tile = blockIdx.x * 4 + wave; tile < ntile; tile += nblk * 4)
        conv_tile(featH, pc, perm, g, sW, out, n, tile, m, hf, bval);
}

// ===================== Fallback path (3-dispatch, launch-failure only) =======
__global__ __launch_bounds__(256) void setup_kernel(
        const int* __restrict__ idx, int* __restrict__ g,
        const float* __restrict__ w, _Float16* __restrict__ wH,
        int* __restrict__ counter, int n, int scatter_blocks) {
    if ((int)blockIdx.x < scatter_blocks) {
        int i = blockIdx.x * 256 + threadIdx.x;
        if (i >= n) return;
        int4 v = ((const int4*)idx)[i];
        int lin = ((v.x * DD + v.y) * HH + v.z) * WW + v.w;
        g[lin] = i;
    } else {
        int t = ((int)blockIdx.x - scatter_blocks) * 256 + threadIdx.x;
        if (t == 0) counter[0] = 0;
        if (t >= NW) return;              // t = kk*512 + co*16 + ci
        int ci = t & (CINC - 1);
        int co = (t >> 4) & (COUTC - 1);
        int kk = t >> 9;
        wH[t] = (_Float16)w[(co * CINC + ci) * KVOL + kk];
    }
}

__global__ __launch_bounds__(256) void compact_kernel(
        const int* __restrict__ idx, const float* __restrict__ feat,
        int* __restrict__ g, _Float16* __restrict__ featH,
        int* __restrict__ pc, int* __restrict__ perm,
        int* __restrict__ counter, int n) {
    __shared__ int s_wsum[4];
    __shared__ int s_wbase[4];
    __shared__ int s_base;
    const int t = threadIdx.x;
    const int lane = t & 63;
    const int wv = t >> 6;
    const int base = blockIdx.x * CVB + t * VPT;

    int4 a0 = ((const int4*)(g + base))[0];
    int4 a1 = ((const int4*)(g + base))[1];
    int vals[VPT] = {a0.x, a0.y, a0.z, a0.w, a1.x, a1.y, a1.z, a1.w};
    int pid[VPT], pck[VPT];
    int cnt = 0;
#pragma unroll
    for (int q = 0; q < VPT; ++q) {
        int p = vals[q];
        bool ok = ((unsigned)p < (unsigned)n);
        int pk = 0;
        if (ok) {
            int4 c = ((const int4*)idx)[p];
            int lin = ((c.x * DD + c.y) * HH + c.z) * WW + c.w;
            ok = (lin == base + q);
            pk = (c.x << 21) | (c.y << 14) | (c.z << 7) | c.w;
        }
        pid[q] = ok ? p : -1;
        pck[q] = pk;
        cnt += ok ? 1 : 0;
    }
    int incl = cnt;
#pragma unroll
    for (int d = 1; d < 64; d <<= 1) {
        int v = __shfl_up(incl, d);
        if (lane >= d) incl += v;
    }
    if (lane == 63) s_wsum[wv] = incl;
    __syncthreads();
    if (t == 0) {
        int t0 = s_wsum[0], t1 = s_wsum[1], t2 = s_wsum[2], t3 = s_wsum[3];
        s_wbase[0] = 0; s_wbase[1] = t0; s_wbase[2] = t0 + t1;
        s_wbase[3] = t0 + t1 + t2;
        s_base = atomicAdd(counter, t0 + t1 + t2 + t3);
    }
    __syncthreads();
    int o = s_base + s_wbase[wv] + incl - cnt;
#pragma unroll
    for (int q = 0; q < VPT; ++q) {
        int tag = n;
        int p = pid[q];
        if (p >= 0) {
            pc[o] = pck[q];
            perm[o] = p;
            const float4* src = (const float4*)(feat + (size_t)p * CINC);
            float4 f0 = src[0], f1 = src[1], f2 = src[2], f3 = src[3];
            half8 h0, h1;
            h0[0]=(_Float16)f0.x; h0[1]=(_Float16)f0.y; h0[2]=(_Float16)f0.z; h0[3]=(_Float16)f0.w;
            h0[4]=(_Float16)f1.x; h0[5]=(_Float16)f1.y; h0[6]=(_Float16)f1.z; h0[7]=(_Float16)f1.w;
            h1[0]=(_Float16)f2.x; h1[1]=(_Float16)f2.y; h1[2]=(_Float16)f2.z; h1[3]=(_Float16)f2.w;
            h1[4]=(_Float16)f3.x; h1[5]=(_Float16)f3.y; h1[6]=(_Float16)f3.z; h1[7]=(_Float16)f3.w;
            half8* dst = (half8*)(featH + (size_t)o * CINC);
            dst[0] = h0; dst[1] = h1;
            tag = o;
            ++o;
        }
        g[base + q] = tag;
    }
    if (blockIdx.x == 0 && t == 0) {
        half8* zr = (half8*)(featH + (size_t)n * CINC);
        half8 hz = {};
        zr[0] = hz; zr[1] = hz;
    }
}

__global__ __launch_bounds__(256, 3) void conv_mfma_kernel(
        const _Float16* __restrict__ featH, const int* __restrict__ pc,
        const int* __restrict__ perm, const _Float16* __restrict__ wH,
        const float* __restrict__ bias, const int* __restrict__ g,
        float* __restrict__ out, int n) {
    __shared__ _Float16 sW[KVOL * 32 * SWP];
    for (int u = threadIdx.x; u < KVOL * 64; u += 256) {
        int kk = u >> 6, r = u & 63;
        int co = r >> 1, h = r & 1;
        const half4* src = (const half4*)(wH + kk * (COUTC * CINC) + co * CINC + h * 8);
        half4 v0 = src[0], v1 = src[1];
        _Float16* dst = &sW[kk * 32 * SWP + co * SWP + h * 8];
        *(half4*)dst = v0;
        *(half4*)(dst + 4) = v1;
    }
    __syncthreads();

    const int lane = threadIdx.x & 63;
    const int wave = threadIdx.x >> 6;
    const int m    = lane & 31;
    const int hf   = lane >> 5;
    const int tile = blockIdx.x * 4 + wave;
    if (tile * 32 >= n) return;
    conv_tile(featH, pc, perm, g, sW, out, n, tile, m, hf, bias[m]);
}

extern "C" void kernel_launch(void* const* d_in, const int* in_sizes, int n_in,
                              void* d_out, int out_size, void* d_ws, size_t ws_size,
                              hipStream_t stream) {
    const float* feat  = (const float*)d_in[0];   // [N,16] fp32
    const int*   idx   = (const int*)d_in[1];     // [N,4]  int32
    const float* convw = (const float*)d_in[2];   // [32,16,3,3,3] fp32
    const float* convb = (const float*)d_in[3];   // [32] fp32
    float* out = (float*)d_out;

    int n = in_sizes[1] / 4;                      // 200000

    // workspace layout (all 16B-aligned)
    char* ws = (char*)d_ws;
    int*      g       = (int*)ws;                               // 7,077,888 B
    int*      counter = (int*)(ws + GRID_VOX * 4);              //       256 B pad
    int*      pc      = (int*)(ws + GRID_VOX * 4 + 256);        //   n*4 B
    int*      perm    = pc + n;                                 //   n*4 B
    _Float16* featH   = (_Float16*)(perm + n);                  // (n+1)*32 B
    _Float16* wH      = featH + (size_t)(n + 1) * CINC;         //  NW*2 B (fallback)

    // Size the cooperative grid from the runtime's own occupancy math
    // (host-side queries only — capture-safe).
    int dev = 0, ncu = 0, maxb = 0;
    hipGetDevice(&dev);
    hipDeviceGetAttribute(&ncu, hipDeviceAttributeMultiprocessorCount, dev);
    hipError_t oe = hipOccupancyMaxActiveBlocksPerMultiprocessor(
        &maxb, fused_kernel, 256, 0);

    hipError_t le = hipErrorUnknown;
    if (oe == hipSuccess && maxb > 0 && ncu > 0) {
        int nblk = maxb * ncu;
        if (nblk > 2048) nblk = 2048;
        void* args[] = { (void*)&feat, (void*)&idx, (void*)&convw, (void*)&convb,
                         (void*)&g, (void*)&featH, (void*)&pc, (void*)&perm,
                         (void*)&counter, (void*)&out, (void*)&n };
        le = hipLaunchCooperativeKernel((void*)fused_kernel,
                                        dim3(nblk), dim3(256), args, 0, stream);
    }

    if (le != hipSuccess) {
        // 3-dispatch fallback.
        const int sb = (n + 255) / 256;
        const int rb = (NW + 255) / 256;
        setup_kernel<<<sb + rb, 256, 0, stream>>>(idx, g, convw, wH, counter, n, sb);
        compact_kernel<<<GRID_VOX / CVB, 256, 0, stream>>>(
            idx, feat, g, featH, pc, perm, counter, n);
        const int waves = (n + 31) / 32;
        conv_mfma_kernel<<<(waves + 3) / 4, 256, 0, stream>>>(
            featH, pc, perm, wH, convb, g, out, n);
    }
}